// Round 10
// baseline (21.304 us; speedup 1.0000x reference)
//
#include <hip/hip_runtime.h>

#define NROWS 4096
#define DDIM  256
#define BDIM  16
#define RBLKS 256           // row-blocks, 16 rows each
#define BSETS 4             // 4 instances per block
#define NB1   (RBLKS * BSETS)  // 1024 blocks = 4 blocks/CU (one generation @16 waves/CU)

// Kernel 1. Balanced decode (holds under linear AND XCD-round-robin dispatch):
//   rblk = i>>2, bset = ((i&3) + (i>>8)) & 3  -> every CU sees all 4 bsets at
//   stratified rows. Wave: 4 groups of 16 lanes; group g owns row n; lane j
//   covers cols {4j+64m} (256 B contiguous per group per load -> coalesced).
// NEW in R10: explicit 2-stage software pipeline. Each stage batches all 8
// float4 loads of one (row, instance) into named registers BEFORE any use, and
// the next stage's loads are issued before the current stage's reduce. This
// lifts VGPR use from 36 (compiler had to serialize loads into ~4 dependent
// memory rounds) to ~100 (16 float4 in flight) for real memory-level
// parallelism per wave.
__global__ __launch_bounds__(256) void cos_partial_kernel(
    const float* __restrict__ stat, const float* __restrict__ con,
    const int* __restrict__ lens, float* __restrict__ ws) {
  const int i    = blockIdx.x;
  const int rblk = i >> 2;                     // 0..255
  const int bset = ((i & 3) + (i >> 8)) & 3;   // 0..3
  const int wave = threadIdx.x >> 6;
  const int lane = threadIdx.x & 63;
  const int g    = lane >> 4;
  const int j    = lane & 15;
  const int n    = rblk * 16 + wave * 4 + g;   // this lane's row
  const int b0   = bset * 4;

  const int L0 = lens[b0 + 0];
  const int L1 = lens[b0 + 1];
  const int L2 = lens[b0 + 2];
  const int L3 = lens[b0 + 3];

  // Issue all 8 loads of one (instance, row) back-to-back into caller regs.
  auto LOADS = [&](int b, int len,
                   float4& x0, float4& x1, float4& x2, float4& x3,
                   float4& y0, float4& y1, float4& y2, float4& y3) {
    if (n < len) {
      const size_t base = (size_t)b * (NROWS * DDIM) + (size_t)n * DDIM + (j << 2);
      const float* pa = stat + base;
      const float* pc = con + base;
      x0 = *reinterpret_cast<const float4*>(pa);
      x1 = *reinterpret_cast<const float4*>(pa + 64);
      x2 = *reinterpret_cast<const float4*>(pa + 128);
      x3 = *reinterpret_cast<const float4*>(pa + 192);
      y0 = *reinterpret_cast<const float4*>(pc);
      y1 = *reinterpret_cast<const float4*>(pc + 64);
      y2 = *reinterpret_cast<const float4*>(pc + 128);
      y3 = *reinterpret_cast<const float4*>(pc + 192);
    } else {
      x0 = x1 = x2 = x3 = make_float4(0.f, 0.f, 0.f, 0.f);
      y0 = y1 = y2 = y3 = make_float4(1.f, 1.f, 1.f, 1.f);  // avoids 0/0
    }
  };

  auto COMP = [&](int len,
                  const float4& x0, const float4& x1, const float4& x2, const float4& x3,
                  const float4& y0, const float4& y1, const float4& y2, const float4& y3) -> float {
    float dot = 0.f, ns = 0.f, nc = 0.f;
    const float4 xs[4] = {x0, x1, x2, x3};
    const float4 ys[4] = {y0, y1, y2, y3};
    #pragma unroll
    for (int m = 0; m < 4; ++m) {
      const float4 a = xs[m], c = ys[m];
      dot = fmaf(a.x, c.x, fmaf(a.y, c.y, fmaf(a.z, c.z, fmaf(a.w, c.w, dot))));
      ns  = fmaf(a.x, a.x, fmaf(a.y, a.y, fmaf(a.z, a.z, fmaf(a.w, a.w, ns))));
      nc  = fmaf(c.x, c.x, fmaf(c.y, c.y, fmaf(c.z, c.z, fmaf(c.w, c.w, nc))));
    }
    #pragma unroll
    for (int off = 1; off < 16; off <<= 1) {   // 4-stage, within 16-lane group
      dot += __shfl_xor(dot, off);
      ns  += __shfl_xor(ns,  off);
      nc  += __shfl_xor(nc,  off);
    }
    float cosv = (n < len) ? dot * rsqrtf(ns) * rsqrtf(nc) : 0.0f;
    cosv += __shfl_xor(cosv, 16);              // sum the wave's 4 row-groups
    cosv += __shfl_xor(cosv, 32);
    return cosv;
  };

  // Two named register stages (8 float4 each); depth-2 pipeline:
  // L(0) L(1) C(0) L(2) C(1) L(3) C(2) C(3)
  float4 Ax0, Ax1, Ax2, Ax3, Ay0, Ay1, Ay2, Ay3;
  float4 Bx0, Bx1, Bx2, Bx3, By0, By1, By2, By3;
  float acc0, acc1, acc2, acc3;

  LOADS(b0 + 0, L0, Ax0, Ax1, Ax2, Ax3, Ay0, Ay1, Ay2, Ay3);
  LOADS(b0 + 1, L1, Bx0, Bx1, Bx2, Bx3, By0, By1, By2, By3);
  acc0 = COMP(L0, Ax0, Ax1, Ax2, Ax3, Ay0, Ay1, Ay2, Ay3);
  LOADS(b0 + 2, L2, Ax0, Ax1, Ax2, Ax3, Ay0, Ay1, Ay2, Ay3);
  acc1 = COMP(L1, Bx0, Bx1, Bx2, Bx3, By0, By1, By2, By3);
  LOADS(b0 + 3, L3, Bx0, Bx1, Bx2, Bx3, By0, By1, By2, By3);
  acc2 = COMP(L2, Ax0, Ax1, Ax2, Ax3, Ay0, Ay1, Ay2, Ay3);
  acc3 = COMP(L3, Bx0, Bx1, Bx2, Bx3, By0, By1, By2, By3);

  __shared__ float sh[4][4];
  if (lane == 0) {
    sh[wave][0] = acc0; sh[wave][1] = acc1; sh[wave][2] = acc2; sh[wave][3] = acc3;
  }
  __syncthreads();
  if (threadIdx.x < 4) {
    const int b = b0 + threadIdx.x;
    ws[b * RBLKS + rblk] =
        sh[0][threadIdx.x] + sh[1][threadIdx.x] + sh[2][threadIdx.x] + sh[3][threadIdx.x];
  }
}

// Kernel 2: one block, 256 threads. Wave w reduces instances 4w..4w+3
// (coalesced reads of 256 partials each), thread 0 combines sequentially.
__global__ __launch_bounds__(256) void cos_final_kernel(
    const float* __restrict__ ws, const int* __restrict__ lens,
    float* __restrict__ out, int B) {
  const int wave = threadIdx.x >> 6;
  const int lane = threadIdx.x & 63;

  __shared__ float shl[BDIM];

  #pragma unroll
  for (int bi = 0; bi < 4; ++bi) {
    const int b = wave * 4 + bi;
    float v = 0.0f;
    #pragma unroll
    for (int m = 0; m < RBLKS / 64; ++m) v += ws[b * RBLKS + (m << 6) + lane];
    #pragma unroll
    for (int off = 1; off < 64; off <<= 1) v += __shfl_xor(v, off);
    if (lane == 0) {
      const int len = lens[b];
      shl[b] = (len > 0) ? (1.0f - v / (float)len) : 0.0f;
    }
  }
  __syncthreads();
  if (threadIdx.x == 0) {
    float t = 0.0f;
    #pragma unroll
    for (int i = 0; i < BDIM; ++i) t += shl[i];
    out[0] = t * (1.0f / BDIM);
  }
}

extern "C" void kernel_launch(void* const* d_in, const int* in_sizes, int n_in,
                              void* d_out, int out_size, void* d_ws, size_t ws_size,
                              hipStream_t stream) {
  const float* stat = (const float*)d_in[0];
  const float* con  = (const float*)d_in[1];
  const int*   lens = (const int*)d_in[2];
  float*       out  = (float*)d_out;
  float*       ws   = (float*)d_ws;

  const int B = in_sizes[2];           // 16

  dim3 grid1(NB1);
  dim3 blk1(256);
  hipLaunchKernelGGL(cos_partial_kernel, grid1, blk1, 0, stream, stat, con, lens, ws);

  dim3 grid2(1);
  dim3 blk2(256);
  hipLaunchKernelGGL(cos_final_kernel, grid2, blk2, 0, stream, ws, lens, out, B);
}